// Round 5
// baseline (753.853 us; speedup 1.0000x reference)
//
#include <hip/hip_runtime.h>
#include <hip/hip_bf16.h>
#include <math.h>

#define B_    4
#define L_    16384
#define DM    96
#define DI    96
#define NS    64
#define RK    6
#define KG_   4
#define CDIM  134   // RK + 2*NS

#define CL    512   // scan chunk length
#define NC    32    // chunks (CL*NC == L_)
#define NWARM 64    // warmup steps re-run from h=0 (decay ~e^-0.7/step -> e^-45)
#define STG   32    // LDS staging depth (steps)

typedef float f32x2 __attribute__((ext_vector_type(2)));
typedef float f32x4 __attribute__((ext_vector_type(4)));

#if defined(__has_builtin)
# if __has_builtin(__builtin_amdgcn_exp2f)
#  define EXP2F(x) __builtin_amdgcn_exp2f(x)
# else
#  define EXP2F(x) exp2f(x)
# endif
#else
# define EXP2F(x) exp2f(x)
#endif

__device__ __forceinline__ float gelu_f(float v) {
  return 0.5f * v * (1.0f + erff(v * 0.70710678118654752f));
}

// ---------------- K1: fused in_proj GEMM + depthwise conv3 + gelu ---------
// cs = blockIdx.y: 0 -> x-half (conv+gelu -> xxc), 1 -> z-half (gelu -> zg).
// Computes an 80-row padded product tile for rows l0-1 .. l0+64 (clamped),
// so the conv halo never leaves LDS and the xz intermediate is eliminated.
__global__ __launch_bounds__(256) void k_front(
    const float* __restrict__ x, const float* __restrict__ w,
    const float* __restrict__ cw,
    float* __restrict__ xxc, float* __restrict__ zg)
{
  __shared__ float sx[80][100];
  __shared__ float sw[96][100];   // W half; reused as product tile [80][100]
  const int tid = threadIdx.x;
  const int lt = blockIdx.x, cs = blockIdx.y, b = blockIdx.z;
  const int l0 = lt * 64;
  const int lbase = l0 - 1;

  for (int i = tid; i < 80 * 24; i += 256) {
    const int r = i / 24, q = i % 24;
    int l = lbase + r; l = l < 0 ? 0 : (l >= L_ ? L_ - 1 : l);
    const float4 v = reinterpret_cast<const float4*>(x + ((size_t)b * L_ + l) * DM)[q];
    *reinterpret_cast<float4*>(&sx[r][q * 4]) = v;
  }
  const float* wp = w + (size_t)cs * 96 * DM;
  for (int i = tid; i < 96 * 24; i += 256) {
    const int r = i / 24, q = i % 24;
    const float4 v = reinterpret_cast<const float4*>(wp + (size_t)r * DM)[q];
    *reinterpret_cast<float4*>(&sw[r][q * 4]) = v;
  }
  __syncthreads();

  const int rg = tid & 15, cg = tid >> 4;
  float acc[5][6];
#pragma unroll
  for (int i = 0; i < 5; ++i)
#pragma unroll
    for (int jj = 0; jj < 6; ++jj) acc[i][jj] = 0.f;

  for (int d0 = 0; d0 < 96; d0 += 4) {
    float4 a[5], wv[6];
#pragma unroll
    for (int i = 0; i < 5; ++i)
      a[i] = *reinterpret_cast<const float4*>(&sx[rg + 16 * i][d0]);
#pragma unroll
    for (int jj = 0; jj < 6; ++jj)
      wv[jj] = *reinterpret_cast<const float4*>(&sw[cg + 16 * jj][d0]);
#pragma unroll
    for (int i = 0; i < 5; ++i)
#pragma unroll
      for (int jj = 0; jj < 6; ++jj)
        acc[i][jj] += a[i].x * wv[jj].x + a[i].y * wv[jj].y
                    + a[i].z * wv[jj].z + a[i].w * wv[jj].w;
  }

  __syncthreads();
  float* sprod = &sw[0][0];  // reuse as [80][100]
#pragma unroll
  for (int i = 0; i < 5; ++i)
#pragma unroll
    for (int jj = 0; jj < 6; ++jj)
      sprod[(rg + 16 * i) * 100 + (cg + 16 * jj)] = acc[i][jj];
  __syncthreads();

  if (cs == 0) {
    // conv3 ('same', zero pad) + gelu -> xxc rows l0..l0+63
    float* op = xxc + ((size_t)b * L_ + l0) * DI;
    for (int i = tid; i < 64 * 24; i += 256) {
      const int ro = i / 24, q = i % 24;
      const int lo = l0 + ro;
      const float4 xm4 = *reinterpret_cast<const float4*>(&sprod[ro * 100 + q * 4]);
      const float4 x04 = *reinterpret_cast<const float4*>(&sprod[(ro + 1) * 100 + q * 4]);
      const float4 xq4 = *reinterpret_cast<const float4*>(&sprod[(ro + 2) * 100 + q * 4]);
      const float mzero = (lo > 0) ? 1.f : 0.f;
      const float qzero = (lo < L_ - 1) ? 1.f : 0.f;
      float4 o;
      {
        const int d0 = q * 4;
        const float* c = cw + d0 * 3;
        o.x = gelu_f(c[0] * xm4.x * mzero + c[1]  * x04.x + c[2]  * xq4.x * qzero);
        o.y = gelu_f(c[3] * xm4.y * mzero + c[4]  * x04.y + c[5]  * xq4.y * qzero);
        o.z = gelu_f(c[6] * xm4.z * mzero + c[7]  * x04.z + c[8]  * xq4.z * qzero);
        o.w = gelu_f(c[9] * xm4.w * mzero + c[10] * x04.w + c[11] * xq4.w * qzero);
      }
      reinterpret_cast<float4*>(op + (size_t)ro * DI)[q] = o;
    }
  } else {
    // gelu(z) -> zg rows l0..l0+63  (product row r = ro+1)
    float* op = zg + ((size_t)b * L_ + l0) * DI;
    for (int i = tid; i < 64 * 24; i += 256) {
      const int ro = i / 24, q = i % 24;
      const float4 v = *reinterpret_cast<const float4*>(&sprod[(ro + 1) * 100 + q * 4]);
      float4 o;
      o.x = gelu_f(v.x); o.y = gelu_f(v.y); o.z = gelu_f(v.z); o.w = gelu_f(v.w);
      reinterpret_cast<float4*>(op + (size_t)ro * DI)[q] = o;
    }
  }
}

// ---------------- K3: x_proj + dt_proj + softplus -> delta/B/C (bf16) ----
__global__ __launch_bounds__(256) void k_xproj(
    const float* __restrict__ xxc, const float* __restrict__ xpw,
    const float* __restrict__ dtw,
    __hip_bfloat16* __restrict__ delta, __hip_bfloat16* __restrict__ Bs,
    __hip_bfloat16* __restrict__ Cs)
{
  __shared__ float sx[32][100];
  __shared__ float sw[144][100];
  __shared__ float sdts[32][8];
  const int tid = threadIdx.x;
  const int lt = blockIdx.x, k = blockIdx.y, b = blockIdx.z;
  const int l0 = lt * 32;
  const bool rev = (k & 1) != 0;

  for (int i = tid; i < 32 * 24; i += 256) {
    const int r = i / 24, q = i % 24;
    const int l = l0 + r;
    const int p = rev ? (L_ - 1 - l) : l;
    const float4 v = reinterpret_cast<const float4*>(xxc + ((size_t)b * L_ + p) * DI)[q];
    *reinterpret_cast<float4*>(&sx[r][q * 4]) = v;
  }
  const float* wp = xpw + (size_t)k * CDIM * DI;
  for (int i = tid; i < 144 * 24; i += 256) {
    const int r = i / 24, q = i % 24;
    float4 v = make_float4(0.f, 0.f, 0.f, 0.f);
    if (r < CDIM) v = reinterpret_cast<const float4*>(wp + (size_t)r * DI)[q];
    *reinterpret_cast<float4*>(&sw[r][q * 4]) = v;
  }
  __syncthreads();

  const int rg = tid & 15, cg = tid >> 4;
  float acc[2][9];
#pragma unroll
  for (int i = 0; i < 2; ++i)
#pragma unroll
    for (int jj = 0; jj < 9; ++jj) acc[i][jj] = 0.f;

  for (int d0 = 0; d0 < 96; d0 += 4) {
    float4 a[2], wv[9];
#pragma unroll
    for (int i = 0; i < 2; ++i)
      a[i] = *reinterpret_cast<const float4*>(&sx[rg + 16 * i][d0]);
#pragma unroll
    for (int jj = 0; jj < 9; ++jj)
      wv[jj] = *reinterpret_cast<const float4*>(&sw[cg + 16 * jj][d0]);
#pragma unroll
    for (int i = 0; i < 2; ++i)
#pragma unroll
      for (int jj = 0; jj < 9; ++jj)
        acc[i][jj] += a[i].x * wv[jj].x + a[i].y * wv[jj].y
                    + a[i].z * wv[jj].z + a[i].w * wv[jj].w;
  }

  __syncthreads();
  float* sB = &sw[0][0];            // [32][68] padded
  float* sC = &sw[0][0] + 32 * 68;  // [32][68] padded
#pragma unroll
  for (int i = 0; i < 2; ++i) {
    const int l = rg + 16 * i;
#pragma unroll
    for (int jj = 0; jj < 9; ++jj) {
      const int c = cg + 16 * jj;
      const float v = acc[i][jj];
      if (c < RK) sdts[l][c] = v;
      else if (c < RK + NS) sB[l * 68 + (c - RK)] = v;
      else if (c < CDIM)    sC[l * 68 + (c - RK - NS)] = v;
    }
  }
  __syncthreads();
  {
    const size_t gbase = (((size_t)(b * KG_ + k)) * L_ + l0) * NS;
    for (int i = tid; i < 32 * 64; i += 256) {
      const int l = i / 64, c = i % 64;
      Bs[gbase + i] = __float2bfloat16(sB[l * 68 + c]);
      Cs[gbase + i] = __float2bfloat16(sC[l * 68 + c]);
    }
  }
  __syncthreads();  // protect sw reuse below vs reads above

  float acc2[2][6];
#pragma unroll
  for (int i = 0; i < 2; ++i)
#pragma unroll
    for (int jj = 0; jj < 6; ++jj) acc2[i][jj] = 0.f;
#pragma unroll
  for (int r = 0; r < RK; ++r) {
    float wc[6];
#pragma unroll
    for (int jj = 0; jj < 6; ++jj)
      wc[jj] = dtw[((size_t)k * DI + (cg + 16 * jj)) * RK + r];
#pragma unroll
    for (int i = 0; i < 2; ++i) {
      const float aa = sdts[rg + 16 * i][r];
#pragma unroll
      for (int jj = 0; jj < 6; ++jj) acc2[i][jj] += aa * wc[jj];
    }
  }
  float* sD = &sw[0][0];  // [32][100]
#pragma unroll
  for (int i = 0; i < 2; ++i)
#pragma unroll
    for (int jj = 0; jj < 6; ++jj) {
      const float v = acc2[i][jj];
      const float sp = (v > 20.f) ? v : log1pf(__expf(v));
      sD[(rg + 16 * i) * 100 + (cg + 16 * jj)] = sp;
    }
  __syncthreads();
  {
    const size_t gbase = (((size_t)(b * KG_ + k)) * L_ + l0) * DI;
    for (int i = tid; i < 32 * 96; i += 256) {
      const int l = i / 96, c = i % 96;
      delta[gbase + i] = __float2bfloat16(sD[l * 100 + c]);
    }
  }
}

// ---------------- K4: chunked selective scan with warmup ------------------
__global__ __launch_bounds__(768) void k_scan(
    const float* __restrict__ xxc,
    const __hip_bfloat16* __restrict__ delta,
    const __hip_bfloat16* __restrict__ Bs,
    const __hip_bfloat16* __restrict__ Cs,
    const float* __restrict__ A_logs, const float* __restrict__ Ds,
    float* __restrict__ ysum)
{
  __shared__ __align__(16) float s_du[STG][192];  // interleaved (delta, u)
  __shared__ __align__(16) float s_B[STG][64];
  __shared__ __align__(16) float s_C[STG][64];
  __shared__ __align__(16) float s_y[STG][96];
  const int tid = threadIdx.x;
  const int ci = blockIdx.x, k = blockIdx.y, b = blockIdx.z;
  const int d = tid >> 3, j = tid & 7;
  const int jn = j * 8;
  const bool rev = (k & 1) != 0;
  const float LOG2E = 1.4426950408889634f;

  f32x2 a2[4], h[4];
#pragma unroll
  for (int p = 0; p < 4; ++p) {
    const int n = jn + 2 * p;
    a2[p].x = -__expf(A_logs[((size_t)(k * DI + d)) * NS + n])     * LOG2E;
    a2[p].y = -__expf(A_logs[((size_t)(k * DI + d)) * NS + n + 1]) * LOG2E;
    h[p].x = 0.f; h[p].y = 0.f;
  }
  const float Dkd = Ds[k * DI + d];

  const int emit0 = ci * CL;
  const int lstart = (emit0 - NWARM > 0) ? (emit0 - NWARM) : 0;
  const int lend = emit0 + CL;
  const size_t bk = (size_t)(b * KG_ + k);

  for (int s = lstart; s < lend; s += STG) {
    __syncthreads();
    {
      const size_t dbase = (bk * L_ + s) * DI;
      for (int i = tid; i < STG * 96; i += 768) {
        const int t = i / 96, dd = i - t * 96;
        const int l = s + t;
        const int p2 = rev ? (L_ - 1 - l) : l;
        s_du[t][2 * dd]     = __bfloat162float(delta[dbase + i]);
        s_du[t][2 * dd + 1] = xxc[((size_t)b * L_ + p2) * DI + dd];
      }
      const size_t nbase = (bk * L_ + s) * NS;
      for (int i = tid; i < STG * 64; i += 768) {
        s_B[i / 64][i % 64] = __bfloat162float(Bs[nbase + i]);
        s_C[i / 64][i % 64] = __bfloat162float(Cs[nbase + i]);
      }
    }
    __syncthreads();
    const bool emit = (s >= emit0);
    for (int t = 0; t < STG; ++t) {
      const f32x2 du = *(const f32x2*)&s_du[t][2 * d];
      const float dlt = du.x, uu = du.y;
      const float bu = dlt * uu;
      const f32x2 dlt2 = {dlt, dlt};
      const f32x2 bu2 = {bu, bu};
      const f32x4 Bv0 = *(const f32x4*)&s_B[t][jn];
      const f32x4 Bv1 = *(const f32x4*)&s_B[t][jn + 4];
      const f32x4 Cv0 = *(const f32x4*)&s_C[t][jn];
      const f32x4 Cv1 = *(const f32x4*)&s_C[t][jn + 4];
      const f32x2 bp[4] = {{Bv0.x, Bv0.y}, {Bv0.z, Bv0.w},
                           {Bv1.x, Bv1.y}, {Bv1.z, Bv1.w}};
      const f32x2 cp[4] = {{Cv0.x, Cv0.y}, {Cv0.z, Cv0.w},
                           {Cv1.x, Cv1.y}, {Cv1.z, Cv1.w}};
      f32x2 y2 = {0.f, 0.f};
#pragma unroll
      for (int p = 0; p < 4; ++p) {
        const f32x2 arg = dlt2 * a2[p];
        f32x2 e;
        e.x = EXP2F(arg.x);
        e.y = EXP2F(arg.y);
        h[p] = e * h[p] + bu2 * bp[p];
        y2 += h[p] * cp[p];
      }
      float y = y2.x + y2.y;
      y += __shfl_xor(y, 1);
      y += __shfl_xor(y, 2);
      y += __shfl_xor(y, 4);
      if (emit && j == 0) s_y[t][d] = fmaf(Dkd, uu, y);
    }
    if (emit) {
      __syncthreads();
      for (int i = tid; i < STG * 96; i += 768) {
        const int t = i / 96, dd = i - t * 96;
        const int l = s + t;
        const int p2 = rev ? (L_ - 1 - l) : l;
        atomicAdd(&ysum[((size_t)b * L_ + p2) * DI + dd], s_y[t][dd]);
      }
    }
  }
}

// ---------------- K5: out = (ysum .* zg) @ Wout^T -------------------------
__global__ __launch_bounds__(256) void k_out(
    const float* __restrict__ ysum, const float* __restrict__ zg,
    const float* __restrict__ wout, float* __restrict__ out)
{
  __shared__ float sa[64][100];
  __shared__ float sw[96][100];
  const int tid = threadIdx.x;
  const int lt = blockIdx.x, b = blockIdx.y;
  const int l0 = lt * 64;
  const size_t rbase = ((size_t)b * L_ + l0) * DI;

  for (int i = tid; i < 64 * 24; i += 256) {
    const int r = i / 24, q = i % 24;
    float4 av = reinterpret_cast<const float4*>(ysum + rbase + (size_t)r * DI)[q];
    const float4 zv = reinterpret_cast<const float4*>(zg + rbase + (size_t)r * DI)[q];
    av.x *= zv.x; av.y *= zv.y; av.z *= zv.z; av.w *= zv.w;
    *reinterpret_cast<float4*>(&sa[r][q * 4]) = av;
  }
  for (int i = tid; i < 96 * 24; i += 256) {
    const int r = i / 24, q = i % 24;
    const float4 v = reinterpret_cast<const float4*>(wout + (size_t)r * DM)[q];
    *reinterpret_cast<float4*>(&sw[r][q * 4]) = v;
  }
  __syncthreads();

  const int rg = tid & 15, cg = tid >> 4;
  float acc[4][6];
#pragma unroll
  for (int i = 0; i < 4; ++i)
#pragma unroll
    for (int jj = 0; jj < 6; ++jj) acc[i][jj] = 0.f;

  for (int d0 = 0; d0 < 96; d0 += 4) {
    float4 a[4], wv[6];
#pragma unroll
    for (int i = 0; i < 4; ++i)
      a[i] = *reinterpret_cast<const float4*>(&sa[rg + 16 * i][d0]);
#pragma unroll
    for (int jj = 0; jj < 6; ++jj)
      wv[jj] = *reinterpret_cast<const float4*>(&sw[cg + 16 * jj][d0]);
#pragma unroll
    for (int i = 0; i < 4; ++i)
#pragma unroll
      for (int jj = 0; jj < 6; ++jj)
        acc[i][jj] += a[i].x * wv[jj].x + a[i].y * wv[jj].y
                    + a[i].z * wv[jj].z + a[i].w * wv[jj].w;
  }

  __syncthreads();
  float* sout = &sw[0][0];  // reuse as [64][100]
#pragma unroll
  for (int i = 0; i < 4; ++i)
#pragma unroll
    for (int jj = 0; jj < 6; ++jj)
      sout[(rg + 16 * i) * 100 + (cg + 16 * jj)] = acc[i][jj];
  __syncthreads();

  float* op = out + ((size_t)b * L_ + l0) * DM;
  for (int i = tid; i < 64 * 24; i += 256) {
    const int r = i / 24, q = i % 24;
    const float4 v = *reinterpret_cast<const float4*>(&sout[r * 100 + q * 4]);
    reinterpret_cast<float4*>(op + (size_t)r * DM)[q] = v;
  }
}

extern "C" void kernel_launch(void* const* d_in, const int* in_sizes, int n_in,
                              void* d_out, int out_size, void* d_ws, size_t ws_size,
                              hipStream_t stream)
{
  const float* x    = (const float*)d_in[0];
  const float* ipw  = (const float*)d_in[1];
  const float* cw   = (const float*)d_in[2];
  const float* xpw  = (const float*)d_in[3];
  const float* dtw  = (const float*)d_in[4];
  const float* opw  = (const float*)d_in[5];
  const float* alog = (const float*)d_in[6];
  const float* dsv  = (const float*)d_in[7];
  float* out = (float*)d_out;
  char* ws = (char*)d_ws;

  const size_t SZ_XZ  = (size_t)B_ * L_ * 192 * 4;      // region reserved (delta lives here)
  const size_t SZ_F   = (size_t)B_ * L_ * DI * 4;       // 25,165,824
  const size_t SZ_NBF = (size_t)B_ * KG_ * L_ * NS * 2; // 33,554,432

  __hip_bfloat16* dlt  = (__hip_bfloat16*)ws;
  float* xxc           = (float*)(ws + SZ_XZ);
  float* zgp           = (float*)(ws + SZ_XZ + SZ_F);
  __hip_bfloat16* Bsp  = (__hip_bfloat16*)(ws + SZ_XZ + 2 * SZ_F);
  __hip_bfloat16* Csp  = (__hip_bfloat16*)(ws + SZ_XZ + 2 * SZ_F + SZ_NBF);
  float* ysum          = (float*)(ws + SZ_XZ + 2 * SZ_F + 2 * SZ_NBF);

  hipMemsetAsync(ysum, 0, SZ_F, stream);
  k_front  <<<dim3(L_ / 64, 2, B_),  256, 0, stream>>>(x, ipw, cw, xxc, zgp);
  k_xproj  <<<dim3(L_ / 32, KG_, B_), 256, 0, stream>>>(xxc, xpw, dtw, dlt, Bsp, Csp);
  k_scan   <<<dim3(NC, KG_, B_),      768, 0, stream>>>(xxc, dlt, Bsp, Csp, alog, dsv, ysum);
  k_out    <<<dim3(L_ / 64, B_),      256, 0, stream>>>(ysum, zgp, opw, out);
}

// Round 6
// 716.452 us; speedup vs baseline: 1.0522x; 1.0522x over previous
//
#include <hip/hip_runtime.h>
#include <hip/hip_bf16.h>
#include <math.h>

#define B_    4
#define L_    16384
#define DM    96
#define DI    96
#define NS    64
#define RK    6
#define KG_   4
#define CDIM  134   // RK + 2*NS

#define CL    512   // scan chunk length
#define NC    32    // chunks (CL*NC == L_)
#define NWARM 64    // warmup steps re-run from h=0 (decay ~e^-0.7/step -> e^-45)
#define STG   32    // LDS staging depth (steps)

typedef float f32x2 __attribute__((ext_vector_type(2)));
typedef float f32x4 __attribute__((ext_vector_type(4)));

#if defined(__has_builtin)
# if __has_builtin(__builtin_amdgcn_exp2f)
#  define EXP2F(x) __builtin_amdgcn_exp2f(x)
# else
#  define EXP2F(x) exp2f(x)
# endif
#else
# define EXP2F(x) exp2f(x)
#endif

__device__ __forceinline__ float gelu_f(float v) {
  return 0.5f * v * (1.0f + erff(v * 0.70710678118654752f));
}

// ---------------- K1: fused in_proj GEMM + depthwise conv3 + gelu ---------
__global__ __launch_bounds__(256) void k_front(
    const float* __restrict__ x, const float* __restrict__ w,
    const float* __restrict__ cw,
    float* __restrict__ xxc, float* __restrict__ zg)
{
  __shared__ float sx[80][100];
  __shared__ float sw[96][100];   // W half; reused as product tile [80][100]
  const int tid = threadIdx.x;
  const int lt = blockIdx.x, cs = blockIdx.y, b = blockIdx.z;
  const int l0 = lt * 64;
  const int lbase = l0 - 1;

  for (int i = tid; i < 80 * 24; i += 256) {
    const int r = i / 24, q = i % 24;
    int l = lbase + r; l = l < 0 ? 0 : (l >= L_ ? L_ - 1 : l);
    const float4 v = reinterpret_cast<const float4*>(x + ((size_t)b * L_ + l) * DM)[q];
    *reinterpret_cast<float4*>(&sx[r][q * 4]) = v;
  }
  const float* wp = w + (size_t)cs * 96 * DM;
  for (int i = tid; i < 96 * 24; i += 256) {
    const int r = i / 24, q = i % 24;
    const float4 v = reinterpret_cast<const float4*>(wp + (size_t)r * DM)[q];
    *reinterpret_cast<float4*>(&sw[r][q * 4]) = v;
  }
  __syncthreads();

  const int rg = tid & 15, cg = tid >> 4;
  float acc[5][6];
#pragma unroll
  for (int i = 0; i < 5; ++i)
#pragma unroll
    for (int jj = 0; jj < 6; ++jj) acc[i][jj] = 0.f;

  for (int d0 = 0; d0 < 96; d0 += 4) {
    float4 a[5], wv[6];
#pragma unroll
    for (int i = 0; i < 5; ++i)
      a[i] = *reinterpret_cast<const float4*>(&sx[rg + 16 * i][d0]);
#pragma unroll
    for (int jj = 0; jj < 6; ++jj)
      wv[jj] = *reinterpret_cast<const float4*>(&sw[cg + 16 * jj][d0]);
#pragma unroll
    for (int i = 0; i < 5; ++i)
#pragma unroll
      for (int jj = 0; jj < 6; ++jj)
        acc[i][jj] += a[i].x * wv[jj].x + a[i].y * wv[jj].y
                    + a[i].z * wv[jj].z + a[i].w * wv[jj].w;
  }

  __syncthreads();
  float* sprod = &sw[0][0];  // reuse as [80][100]
#pragma unroll
  for (int i = 0; i < 5; ++i)
#pragma unroll
    for (int jj = 0; jj < 6; ++jj)
      sprod[(rg + 16 * i) * 100 + (cg + 16 * jj)] = acc[i][jj];
  __syncthreads();

  if (cs == 0) {
    float* op = xxc + ((size_t)b * L_ + l0) * DI;
    for (int i = tid; i < 64 * 24; i += 256) {
      const int ro = i / 24, q = i % 24;
      const int lo = l0 + ro;
      const float4 xm4 = *reinterpret_cast<const float4*>(&sprod[ro * 100 + q * 4]);
      const float4 x04 = *reinterpret_cast<const float4*>(&sprod[(ro + 1) * 100 + q * 4]);
      const float4 xq4 = *reinterpret_cast<const float4*>(&sprod[(ro + 2) * 100 + q * 4]);
      const float mzero = (lo > 0) ? 1.f : 0.f;
      const float qzero = (lo < L_ - 1) ? 1.f : 0.f;
      float4 o;
      {
        const int d0 = q * 4;
        const float* c = cw + d0 * 3;
        o.x = gelu_f(c[0] * xm4.x * mzero + c[1]  * x04.x + c[2]  * xq4.x * qzero);
        o.y = gelu_f(c[3] * xm4.y * mzero + c[4]  * x04.y + c[5]  * xq4.y * qzero);
        o.z = gelu_f(c[6] * xm4.z * mzero + c[7]  * x04.z + c[8]  * xq4.z * qzero);
        o.w = gelu_f(c[9] * xm4.w * mzero + c[10] * x04.w + c[11] * xq4.w * qzero);
      }
      reinterpret_cast<float4*>(op + (size_t)ro * DI)[q] = o;
    }
  } else {
    float* op = zg + ((size_t)b * L_ + l0) * DI;
    for (int i = tid; i < 64 * 24; i += 256) {
      const int ro = i / 24, q = i % 24;
      const float4 v = *reinterpret_cast<const float4*>(&sprod[(ro + 1) * 100 + q * 4]);
      float4 o;
      o.x = gelu_f(v.x); o.y = gelu_f(v.y); o.z = gelu_f(v.z); o.w = gelu_f(v.w);
      reinterpret_cast<float4*>(op + (size_t)ro * DI)[q] = o;
    }
  }
}

// ---------------- K3: x_proj + dt_proj + softplus -> delta/B/C (bf16) ----
__global__ __launch_bounds__(256) void k_xproj(
    const float* __restrict__ xxc, const float* __restrict__ xpw,
    const float* __restrict__ dtw,
    __hip_bfloat16* __restrict__ delta, __hip_bfloat16* __restrict__ Bs,
    __hip_bfloat16* __restrict__ Cs)
{
  __shared__ float sx[32][100];
  __shared__ float sw[144][100];
  __shared__ float sdts[32][8];
  const int tid = threadIdx.x;
  const int lt = blockIdx.x, k = blockIdx.y, b = blockIdx.z;
  const int l0 = lt * 32;
  const bool rev = (k & 1) != 0;

  for (int i = tid; i < 32 * 24; i += 256) {
    const int r = i / 24, q = i % 24;
    const int l = l0 + r;
    const int p = rev ? (L_ - 1 - l) : l;
    const float4 v = reinterpret_cast<const float4*>(xxc + ((size_t)b * L_ + p) * DI)[q];
    *reinterpret_cast<float4*>(&sx[r][q * 4]) = v;
  }
  const float* wp = xpw + (size_t)k * CDIM * DI;
  for (int i = tid; i < 144 * 24; i += 256) {
    const int r = i / 24, q = i % 24;
    float4 v = make_float4(0.f, 0.f, 0.f, 0.f);
    if (r < CDIM) v = reinterpret_cast<const float4*>(wp + (size_t)r * DI)[q];
    *reinterpret_cast<float4*>(&sw[r][q * 4]) = v;
  }
  __syncthreads();

  const int rg = tid & 15, cg = tid >> 4;
  float acc[2][9];
#pragma unroll
  for (int i = 0; i < 2; ++i)
#pragma unroll
    for (int jj = 0; jj < 9; ++jj) acc[i][jj] = 0.f;

  for (int d0 = 0; d0 < 96; d0 += 4) {
    float4 a[2], wv[9];
#pragma unroll
    for (int i = 0; i < 2; ++i)
      a[i] = *reinterpret_cast<const float4*>(&sx[rg + 16 * i][d0]);
#pragma unroll
    for (int jj = 0; jj < 9; ++jj)
      wv[jj] = *reinterpret_cast<const float4*>(&sw[cg + 16 * jj][d0]);
#pragma unroll
    for (int i = 0; i < 2; ++i)
#pragma unroll
      for (int jj = 0; jj < 9; ++jj)
        acc[i][jj] += a[i].x * wv[jj].x + a[i].y * wv[jj].y
                    + a[i].z * wv[jj].z + a[i].w * wv[jj].w;
  }

  __syncthreads();
  float* sB = &sw[0][0];            // [32][68] padded
  float* sC = &sw[0][0] + 32 * 68;  // [32][68] padded
#pragma unroll
  for (int i = 0; i < 2; ++i) {
    const int l = rg + 16 * i;
#pragma unroll
    for (int jj = 0; jj < 9; ++jj) {
      const int c = cg + 16 * jj;
      const float v = acc[i][jj];
      if (c < RK) sdts[l][c] = v;
      else if (c < RK + NS) sB[l * 68 + (c - RK)] = v;
      else if (c < CDIM)    sC[l * 68 + (c - RK - NS)] = v;
    }
  }
  __syncthreads();
  {
    const size_t gbase = (((size_t)(b * KG_ + k)) * L_ + l0) * NS;
    for (int i = tid; i < 32 * 64; i += 256) {
      const int l = i / 64, c = i % 64;
      Bs[gbase + i] = __float2bfloat16(sB[l * 68 + c]);
      Cs[gbase + i] = __float2bfloat16(sC[l * 68 + c]);
    }
  }
  __syncthreads();  // protect sw reuse below vs reads above

  float acc2[2][6];
#pragma unroll
  for (int i = 0; i < 2; ++i)
#pragma unroll
    for (int jj = 0; jj < 6; ++jj) acc2[i][jj] = 0.f;
#pragma unroll
  for (int r = 0; r < RK; ++r) {
    float wc[6];
#pragma unroll
    for (int jj = 0; jj < 6; ++jj)
      wc[jj] = dtw[((size_t)k * DI + (cg + 16 * jj)) * RK + r];
#pragma unroll
    for (int i = 0; i < 2; ++i) {
      const float aa = sdts[rg + 16 * i][r];
#pragma unroll
      for (int jj = 0; jj < 6; ++jj) acc2[i][jj] += aa * wc[jj];
    }
  }
  float* sD = &sw[0][0];  // [32][100]
#pragma unroll
  for (int i = 0; i < 2; ++i)
#pragma unroll
    for (int jj = 0; jj < 6; ++jj) {
      const float v = acc2[i][jj];
      const float sp = (v > 20.f) ? v : log1pf(__expf(v));
      sD[(rg + 16 * i) * 100 + (cg + 16 * jj)] = sp;
    }
  __syncthreads();
  {
    const size_t gbase = (((size_t)(b * KG_ + k)) * L_ + l0) * DI;
    for (int i = tid; i < 32 * 96; i += 256) {
      const int l = i / 96, c = i % 96;
      delta[gbase + i] = __float2bfloat16(sD[l * 100 + c]);
    }
  }
}

// ---------------- K4: chunked selective scan with warmup ------------------
// Hot loop unrolled so LDS addresses fold to base+immediate; staging/flush
// use one-time tid decomposition (no per-iter div/mod); bu = delta*u
// precomputed at staging; D*u term folded into the flush.
__global__ __launch_bounds__(768) void k_scan(
    const float* __restrict__ xxc,
    const __hip_bfloat16* __restrict__ delta,
    const __hip_bfloat16* __restrict__ Bs,
    const __hip_bfloat16* __restrict__ Cs,
    const float* __restrict__ A_logs, const float* __restrict__ Ds,
    float* __restrict__ ysum)
{
  __shared__ __align__(16) float s_du[STG][192];  // interleaved (delta, delta*u)
  __shared__ __align__(16) float s_u[STG][96];
  __shared__ __align__(16) float s_B[STG][64];
  __shared__ __align__(16) float s_C[STG][64];
  __shared__ __align__(16) float s_y[STG][96];
  const int tid = threadIdx.x;
  const int ci = blockIdx.x, k = blockIdx.y, b = blockIdx.z;
  const int d = tid >> 3, j = tid & 7;
  const int jn = j * 8;
  const bool rev = (k & 1) != 0;
  const float LOG2E = 1.4426950408889634f;

  // staging decompositions (computed once)
  const int r96 = tid / 96;          // 0..7
  const int c96 = tid - r96 * 96;    // 0..95
  const int r64 = tid >> 6;          // 0..11
  const int c64 = tid & 63;

  f32x2 a2[4], h[4];
#pragma unroll
  for (int p = 0; p < 4; ++p) {
    const int n = jn + 2 * p;
    a2[p].x = -__expf(A_logs[((size_t)(k * DI + d)) * NS + n])     * LOG2E;
    a2[p].y = -__expf(A_logs[((size_t)(k * DI + d)) * NS + n + 1]) * LOG2E;
    h[p].x = 0.f; h[p].y = 0.f;
  }
  const float Dc = Ds[k * DI + c96];   // for the flush (per-flush-lane D)

  const int emit0 = ci * CL;
  const int lstart = (emit0 - NWARM > 0) ? (emit0 - NWARM) : 0;
  const int lend = emit0 + CL;
  const size_t bk = (size_t)(b * KG_ + k);

  for (int s = lstart; s < lend; s += STG) {
    __syncthreads();
    {
      const size_t dbase = (bk * L_ + s) * DI;
      const int pbase = rev ? (L_ - 1 - s) : s;   // row for t=0
      const int psgn  = rev ? -1 : 1;
      const float* ubase = xxc + ((size_t)b * L_ + pbase) * DI + c96;
#pragma unroll
      for (int it = 0; it < 4; ++it) {
        const int t = r96 + 8 * it;
        const float dl = __bfloat162float(delta[dbase + (size_t)t * DI + c96]);
        const float uu = ubase[(ptrdiff_t)psgn * t * DI];
        f32x2 v; v.x = dl; v.y = dl * uu;
        *(f32x2*)&s_du[t][2 * c96] = v;
        s_u[t][c96] = uu;
      }
      const size_t nbase = (bk * L_ + s) * NS;
#pragma unroll
      for (int it = 0; it < 3; ++it) {
        const int t = r64 + 12 * it;
        if (t < STG) {
          s_B[t][c64] = __bfloat162float(Bs[nbase + (size_t)t * NS + c64]);
          s_C[t][c64] = __bfloat162float(Cs[nbase + (size_t)t * NS + c64]);
        }
      }
    }
    __syncthreads();
    const bool emit = (s >= emit0);
#pragma unroll 8
    for (int t = 0; t < STG; ++t) {
      const f32x2 du = *(const f32x2*)&s_du[t][2 * d];
      const float dlt = du.x, bu = du.y;
      const f32x2 dlt2 = {dlt, dlt};
      const f32x2 bu2 = {bu, bu};
      const f32x4 Bv0 = *(const f32x4*)&s_B[t][jn];
      const f32x4 Bv1 = *(const f32x4*)&s_B[t][jn + 4];
      const f32x4 Cv0 = *(const f32x4*)&s_C[t][jn];
      const f32x4 Cv1 = *(const f32x4*)&s_C[t][jn + 4];
      const f32x2 bp[4] = {{Bv0.x, Bv0.y}, {Bv0.z, Bv0.w},
                           {Bv1.x, Bv1.y}, {Bv1.z, Bv1.w}};
      const f32x2 cp[4] = {{Cv0.x, Cv0.y}, {Cv0.z, Cv0.w},
                           {Cv1.x, Cv1.y}, {Cv1.z, Cv1.w}};
      f32x2 y2 = {0.f, 0.f};
#pragma unroll
      for (int p = 0; p < 4; ++p) {
        const f32x2 arg = dlt2 * a2[p];
        f32x2 e;
        e.x = EXP2F(arg.x);
        e.y = EXP2F(arg.y);
        h[p] = e * h[p] + bu2 * bp[p];
        y2 += h[p] * cp[p];
      }
      float y = y2.x + y2.y;
      y += __shfl_xor(y, 1);
      y += __shfl_xor(y, 2);
      y += __shfl_xor(y, 4);
      if (emit && j == 0) s_y[t][d] = y;
    }
    if (emit) {
      __syncthreads();
      const int pbase = rev ? (L_ - 1 - s) : s;
      const int psgn  = rev ? -1 : 1;
      float* ybase = ysum + ((size_t)b * L_ + pbase) * DI + c96;
#pragma unroll
      for (int it = 0; it < 4; ++it) {
        const int t = r96 + 8 * it;
        atomicAdd(ybase + (ptrdiff_t)psgn * t * DI,
                  fmaf(Dc, s_u[t][c96], s_y[t][c96]));
      }
    }
  }
}

// ---------------- K5: out = (ysum .* zg) @ Wout^T -------------------------
__global__ __launch_bounds__(256) void k_out(
    const float* __restrict__ ysum, const float* __restrict__ zg,
    const float* __restrict__ wout, float* __restrict__ out)
{
  __shared__ float sa[64][100];
  __shared__ float sw[96][100];
  const int tid = threadIdx.x;
  const int lt = blockIdx.x, b = blockIdx.y;
  const int l0 = lt * 64;
  const size_t rbase = ((size_t)b * L_ + l0) * DI;

  for (int i = tid; i < 64 * 24; i += 256) {
    const int r = i / 24, q = i % 24;
    float4 av = reinterpret_cast<const float4*>(ysum + rbase + (size_t)r * DI)[q];
    const float4 zv = reinterpret_cast<const float4*>(zg + rbase + (size_t)r * DI)[q];
    av.x *= zv.x; av.y *= zv.y; av.z *= zv.z; av.w *= zv.w;
    *reinterpret_cast<float4*>(&sa[r][q * 4]) = av;
  }
  for (int i = tid; i < 96 * 24; i += 256) {
    const int r = i / 24, q = i % 24;
    const float4 v = reinterpret_cast<const float4*>(wout + (size_t)r * DM)[q];
    *reinterpret_cast<float4*>(&sw[r][q * 4]) = v;
  }
  __syncthreads();

  const int rg = tid & 15, cg = tid >> 4;
  float acc[4][6];
#pragma unroll
  for (int i = 0; i < 4; ++i)
#pragma unroll
    for (int jj = 0; jj < 6; ++jj) acc[i][jj] = 0.f;

  for (int d0 = 0; d0 < 96; d0 += 4) {
    float4 a[4], wv[6];
#pragma unroll
    for (int i = 0; i < 4; ++i)
      a[i] = *reinterpret_cast<const float4*>(&sa[rg + 16 * i][d0]);
#pragma unroll
    for (int jj = 0; jj < 6; ++jj)
      wv[jj] = *reinterpret_cast<const float4*>(&sw[cg + 16 * jj][d0]);
#pragma unroll
    for (int i = 0; i < 4; ++i)
#pragma unroll
      for (int jj = 0; jj < 6; ++jj)
        acc[i][jj] += a[i].x * wv[jj].x + a[i].y * wv[jj].y
                    + a[i].z * wv[jj].z + a[i].w * wv[jj].w;
  }

  __syncthreads();
  float* sout = &sw[0][0];  // reuse as [64][100]
#pragma unroll
  for (int i = 0; i < 4; ++i)
#pragma unroll
    for (int jj = 0; jj < 6; ++jj)
      sout[(rg + 16 * i) * 100 + (cg + 16 * jj)] = acc[i][jj];
  __syncthreads();

  float* op = out + ((size_t)b * L_ + l0) * DM;
  for (int i = tid; i < 64 * 24; i += 256) {
    const int r = i / 24, q = i % 24;
    const float4 v = *reinterpret_cast<const float4*>(&sout[r * 100 + q * 4]);
    reinterpret_cast<float4*>(op + (size_t)r * DM)[q] = v;
  }
}

extern "C" void kernel_launch(void* const* d_in, const int* in_sizes, int n_in,
                              void* d_out, int out_size, void* d_ws, size_t ws_size,
                              hipStream_t stream)
{
  const float* x    = (const float*)d_in[0];
  const float* ipw  = (const float*)d_in[1];
  const float* cw   = (const float*)d_in[2];
  const float* xpw  = (const float*)d_in[3];
  const float* dtw  = (const float*)d_in[4];
  const float* opw  = (const float*)d_in[5];
  const float* alog = (const float*)d_in[6];
  const float* dsv  = (const float*)d_in[7];
  float* out = (float*)d_out;
  char* ws = (char*)d_ws;

  const size_t SZ_XZ  = (size_t)B_ * L_ * 192 * 4;      // region reserved (delta lives here)
  const size_t SZ_F   = (size_t)B_ * L_ * DI * 4;       // 25,165,824
  const size_t SZ_NBF = (size_t)B_ * KG_ * L_ * NS * 2; // 33,554,432

  __hip_bfloat16* dlt  = (__hip_bfloat16*)ws;
  float* xxc           = (float*)(ws + SZ_XZ);
  float* zgp           = (float*)(ws + SZ_XZ + SZ_F);
  __hip_bfloat16* Bsp  = (__hip_bfloat16*)(ws + SZ_XZ + 2 * SZ_F);
  __hip_bfloat16* Csp  = (__hip_bfloat16*)(ws + SZ_XZ + 2 * SZ_F + SZ_NBF);
  float* ysum          = (float*)(ws + SZ_XZ + 2 * SZ_F + 2 * SZ_NBF);

  hipMemsetAsync(ysum, 0, SZ_F, stream);
  k_front  <<<dim3(L_ / 64, 2, B_),  256, 0, stream>>>(x, ipw, cw, xxc, zgp);
  k_xproj  <<<dim3(L_ / 32, KG_, B_), 256, 0, stream>>>(xxc, xpw, dtw, dlt, Bsp, Csp);
  k_scan   <<<dim3(NC, KG_, B_),      768, 0, stream>>>(xxc, dlt, Bsp, Csp, alog, dsv, ysum);
  k_out    <<<dim3(L_ / 64, B_),      256, 0, stream>>>(ysum, zgp, opw, out);
}

// Round 7
// 536.899 us; speedup vs baseline: 1.4041x; 1.3344x over previous
//
#include <hip/hip_runtime.h>
#include <hip/hip_bf16.h>
#include <math.h>

#define B_    4
#define L_    16384
#define DM    96
#define DI    96
#define NS    64
#define RK    6
#define KG_   4
#define CDIM  134   // RK + 2*NS

#define CL    512   // scan chunk length
#define NC    32    // chunks (CL*NC == L_)
#define NWARM 64    // warmup steps re-run from h=0 (decay ~e^-0.7/step -> e^-45)
#define STG   32    // LDS staging depth (steps)

typedef float f32x2 __attribute__((ext_vector_type(2)));
typedef float f32x4 __attribute__((ext_vector_type(4)));
typedef short bf16x8 __attribute__((ext_vector_type(8)));

#if defined(__has_builtin)
# if __has_builtin(__builtin_amdgcn_exp2f)
#  define EXP2F(x) __builtin_amdgcn_exp2f(x)
# else
#  define EXP2F(x) exp2f(x)
# endif
#else
# define EXP2F(x) exp2f(x)
#endif

__device__ __forceinline__ float gelu_f(float v) {
  return 0.5f * v * (1.0f + erff(v * 0.70710678118654752f));
}

__device__ __forceinline__ unsigned short f2bf(float v) {
  __hip_bfloat16 h = __float2bfloat16(v);
  return *reinterpret_cast<unsigned short*>(&h);
}

// ---------------- K1: fused in_proj GEMM + depthwise conv3 + gelu ---------
__global__ __launch_bounds__(256) void k_front(
    const float* __restrict__ x, const float* __restrict__ w,
    const float* __restrict__ cw,
    float* __restrict__ xxc, float* __restrict__ zg)
{
  __shared__ float sx[80][100];
  __shared__ float sw[96][100];   // W half; reused as product tile [80][100]
  const int tid = threadIdx.x;
  const int lt = blockIdx.x, cs = blockIdx.y, b = blockIdx.z;
  const int l0 = lt * 64;
  const int lbase = l0 - 1;

  for (int i = tid; i < 80 * 24; i += 256) {
    const int r = i / 24, q = i % 24;
    int l = lbase + r; l = l < 0 ? 0 : (l >= L_ ? L_ - 1 : l);
    const float4 v = reinterpret_cast<const float4*>(x + ((size_t)b * L_ + l) * DM)[q];
    *reinterpret_cast<float4*>(&sx[r][q * 4]) = v;
  }
  const float* wp = w + (size_t)cs * 96 * DM;
  for (int i = tid; i < 96 * 24; i += 256) {
    const int r = i / 24, q = i % 24;
    const float4 v = reinterpret_cast<const float4*>(wp + (size_t)r * DM)[q];
    *reinterpret_cast<float4*>(&sw[r][q * 4]) = v;
  }
  __syncthreads();

  const int rg = tid & 15, cg = tid >> 4;
  float acc[5][6];
#pragma unroll
  for (int i = 0; i < 5; ++i)
#pragma unroll
    for (int jj = 0; jj < 6; ++jj) acc[i][jj] = 0.f;

  for (int d0 = 0; d0 < 96; d0 += 4) {
    float4 a[5], wv[6];
#pragma unroll
    for (int i = 0; i < 5; ++i)
      a[i] = *reinterpret_cast<const float4*>(&sx[rg + 16 * i][d0]);
#pragma unroll
    for (int jj = 0; jj < 6; ++jj)
      wv[jj] = *reinterpret_cast<const float4*>(&sw[cg + 16 * jj][d0]);
#pragma unroll
    for (int i = 0; i < 5; ++i)
#pragma unroll
      for (int jj = 0; jj < 6; ++jj)
        acc[i][jj] += a[i].x * wv[jj].x + a[i].y * wv[jj].y
                    + a[i].z * wv[jj].z + a[i].w * wv[jj].w;
  }

  __syncthreads();
  float* sprod = &sw[0][0];  // reuse as [80][100]
#pragma unroll
  for (int i = 0; i < 5; ++i)
#pragma unroll
    for (int jj = 0; jj < 6; ++jj)
      sprod[(rg + 16 * i) * 100 + (cg + 16 * jj)] = acc[i][jj];
  __syncthreads();

  if (cs == 0) {
    float* op = xxc + ((size_t)b * L_ + l0) * DI;
    for (int i = tid; i < 64 * 24; i += 256) {
      const int ro = i / 24, q = i % 24;
      const int lo = l0 + ro;
      const float4 xm4 = *reinterpret_cast<const float4*>(&sprod[ro * 100 + q * 4]);
      const float4 x04 = *reinterpret_cast<const float4*>(&sprod[(ro + 1) * 100 + q * 4]);
      const float4 xq4 = *reinterpret_cast<const float4*>(&sprod[(ro + 2) * 100 + q * 4]);
      const float mzero = (lo > 0) ? 1.f : 0.f;
      const float qzero = (lo < L_ - 1) ? 1.f : 0.f;
      float4 o;
      {
        const int d0 = q * 4;
        const float* c = cw + d0 * 3;
        o.x = gelu_f(c[0] * xm4.x * mzero + c[1]  * x04.x + c[2]  * xq4.x * qzero);
        o.y = gelu_f(c[3] * xm4.y * mzero + c[4]  * x04.y + c[5]  * xq4.y * qzero);
        o.z = gelu_f(c[6] * xm4.z * mzero + c[7]  * x04.z + c[8]  * xq4.z * qzero);
        o.w = gelu_f(c[9] * xm4.w * mzero + c[10] * x04.w + c[11] * xq4.w * qzero);
      }
      reinterpret_cast<float4*>(op + (size_t)ro * DI)[q] = o;
    }
  } else {
    float* op = zg + ((size_t)b * L_ + l0) * DI;
    for (int i = tid; i < 64 * 24; i += 256) {
      const int ro = i / 24, q = i % 24;
      const float4 v = *reinterpret_cast<const float4*>(&sprod[(ro + 1) * 100 + q * 4]);
      float4 o;
      o.x = gelu_f(v.x); o.y = gelu_f(v.y); o.z = gelu_f(v.z); o.w = gelu_f(v.w);
      reinterpret_cast<float4*>(op + (size_t)ro * DI)[q] = o;
    }
  }
}

// ---------------- K3: x_proj + dt_proj + softplus via bf16 MFMA ----------
// Per block: 64 scan-rows x 144 cols (134 real), K=96. 4 waves; wave w owns
// rows [w*16, w*16+16), 9 col-tiles of 16. mfma_f32_16x16x32_bf16, 3 K-slices.
// A/B frags use the same (lane-group, elem)->k map, so the k bijection is
// self-consistent; C/D layout: col=lane&15, row=(lane>>4)*4+reg (m89).
__global__ __launch_bounds__(256) void k_xproj(
    const float* __restrict__ xxc, const float* __restrict__ xpw,
    const float* __restrict__ dtw,
    __hip_bfloat16* __restrict__ delta, __hip_bfloat16* __restrict__ Bs,
    __hip_bfloat16* __restrict__ Cs)
{
  __shared__ __align__(16) unsigned short sxb[64][104];  // x tile bf16 (pad 104)
  __shared__ __align__(16) unsigned short swb[144 * 104];// W bf16 [144][104]; reused post-MFMA
  __shared__ __align__(16) float sdtw[576];              // dt_projs_w[k] (96x6)
  const int tid = threadIdx.x;
  const int lt = blockIdx.x, kdir = blockIdx.y, b = blockIdx.z;
  const int l0 = lt * 64;
  const bool rev = (kdir & 1) != 0;

  // stage dtw
  for (int i = tid; i < 576; i += 256) sdtw[i] = dtw[(size_t)kdir * 576 + i];

  // stage x tile (scan order; fp32 -> bf16)
  for (int i = tid; i < 64 * 24; i += 256) {
    const int r = i / 24, q = i % 24;
    const int l = l0 + r;
    const int p = rev ? (L_ - 1 - l) : l;
    const float4 v = reinterpret_cast<const float4*>(xxc + ((size_t)b * L_ + p) * DI)[q];
    ushort4 u;
    u.x = f2bf(v.x); u.y = f2bf(v.y); u.z = f2bf(v.z); u.w = f2bf(v.w);
    *reinterpret_cast<ushort4*>(&sxb[r][q * 4]) = u;
  }
  // stage W (134 real rows + 10 zero rows), fp32 -> bf16
  const float* wp = xpw + (size_t)kdir * CDIM * DI;
  for (int i = tid; i < 144 * 24; i += 256) {
    const int r = i / 24, q = i % 24;
    float4 v = make_float4(0.f, 0.f, 0.f, 0.f);
    if (r < CDIM) v = reinterpret_cast<const float4*>(wp + (size_t)r * DI)[q];
    ushort4 u;
    u.x = f2bf(v.x); u.y = f2bf(v.y); u.z = f2bf(v.z); u.w = f2bf(v.w);
    *reinterpret_cast<ushort4*>(&swb[r * 104 + q * 4]) = u;
  }
  __syncthreads();

  // ---- MFMA: 9 col-tiles x 3 K-slices per wave
  const int wv = tid >> 6, lane = tid & 63;
  const int m0 = wv * 16;
  const int lrow = lane & 15, lkg = lane >> 4;
  f32x4 acc[9];
#pragma unroll
  for (int n = 0; n < 9; ++n) acc[n] = (f32x4){0.f, 0.f, 0.f, 0.f};

#pragma unroll
  for (int kk = 0; kk < 3; ++kk) {
    const int kbase = kk * 32 + lkg * 8;
    const bf16x8 af = *reinterpret_cast<const bf16x8*>(&sxb[m0 + lrow][kbase]);
#pragma unroll
    for (int n = 0; n < 9; ++n) {
      const bf16x8 bfm = *reinterpret_cast<const bf16x8*>(&swb[(n * 16 + lrow) * 104 + kbase]);
      acc[n] = __builtin_amdgcn_mfma_f32_16x16x32_bf16(af, bfm, acc[n], 0, 0, 0);
    }
  }
  __syncthreads();  // all waves done reading swb; safe to overlay

  // overlay regions inside swb
  unsigned short* soB = swb;               // [64][68] bf16
  unsigned short* soC = swb + 64 * 68;     // [64][68] bf16
  float* sdts = reinterpret_cast<float*>(swb + 2 * 64 * 68);  // [64][8] fp32

  {
    const int row = m0 + lkg * 4;
#pragma unroll
    for (int n = 0; n < 9; ++n) {
      const int c = n * 16 + lrow;
#pragma unroll
      for (int reg = 0; reg < 4; ++reg) {
        const float v = acc[n][reg];
        const int rr = row + reg;
        if (c < RK)            sdts[rr * 8 + c] = v;
        else if (c < RK + NS)  soB[rr * 68 + (c - RK)] = f2bf(v);
        else if (c < CDIM)     soC[rr * 68 + (c - RK - NS)] = f2bf(v);
      }
    }
  }
  __syncthreads();

  const size_t bk = (size_t)(b * KG_ + kdir);
  // coalesced copies: Bs, Cs
  {
    unsigned short* bsg = reinterpret_cast<unsigned short*>(Bs);
    unsigned short* csg = reinterpret_cast<unsigned short*>(Cs);
    const size_t nbase = (bk * L_ + l0) * NS;
    for (int i = tid; i < 64 * 16; i += 256) {
      const int r = i >> 4, q = i & 15;
      const ushort4 vb = *reinterpret_cast<const ushort4*>(&soB[r * 68 + q * 4]);
      const ushort4 vc = *reinterpret_cast<const ushort4*>(&soC[r * 68 + q * 4]);
      *reinterpret_cast<ushort4*>(bsg + nbase + (size_t)r * NS + q * 4) = vb;
      *reinterpret_cast<ushort4*>(csg + nbase + (size_t)r * NS + q * 4) = vc;
    }
  }
  // dt_proj (fp32) + softplus -> delta (bf16)
  {
    unsigned short* dg = reinterpret_cast<unsigned short*>(delta);
    const size_t dbase = (bk * L_ + l0) * DI;
    for (int i = tid; i < 64 * 24; i += 256) {
      const int r = i / 24, q = i - r * 24;
      const int dc0 = q * 4;
      ushort4 u;
      float o[4];
#pragma unroll
      for (int e = 0; e < 4; ++e) {
        const int dc = dc0 + e;
        float s = 0.f;
#pragma unroll
        for (int rr6 = 0; rr6 < RK; ++rr6)
          s += sdts[r * 8 + rr6] * sdtw[dc * RK + rr6];
        o[e] = (s > 20.f) ? s : log1pf(__expf(s));
      }
      u.x = f2bf(o[0]); u.y = f2bf(o[1]); u.z = f2bf(o[2]); u.w = f2bf(o[3]);
      *reinterpret_cast<ushort4*>(dg + dbase + (size_t)r * DI + dc0) = u;
    }
  }
}

// ---------------- K4: chunked selective scan with warmup ------------------
__global__ __launch_bounds__(768) void k_scan(
    const float* __restrict__ xxc,
    const __hip_bfloat16* __restrict__ delta,
    const __hip_bfloat16* __restrict__ Bs,
    const __hip_bfloat16* __restrict__ Cs,
    const float* __restrict__ A_logs, const float* __restrict__ Ds,
    float* __restrict__ ysum)
{
  __shared__ __align__(16) float s_du[STG][192];  // interleaved (delta, delta*u)
  __shared__ __align__(16) float s_u[STG][96];
  __shared__ __align__(16) float s_B[STG][64];
  __shared__ __align__(16) float s_C[STG][64];
  __shared__ __align__(16) float s_y[STG][96];
  const int tid = threadIdx.x;
  const int ci = blockIdx.x, k = blockIdx.y, b = blockIdx.z;
  const int d = tid >> 3, j = tid & 7;
  const int jn = j * 8;
  const bool rev = (k & 1) != 0;
  const float LOG2E = 1.4426950408889634f;

  const int r96 = tid / 96;
  const int c96 = tid - r96 * 96;
  const int r64 = tid >> 6;
  const int c64 = tid & 63;

  f32x2 a2[4], h[4];
#pragma unroll
  for (int p = 0; p < 4; ++p) {
    const int n = jn + 2 * p;
    a2[p].x = -__expf(A_logs[((size_t)(k * DI + d)) * NS + n])     * LOG2E;
    a2[p].y = -__expf(A_logs[((size_t)(k * DI + d)) * NS + n + 1]) * LOG2E;
    h[p].x = 0.f; h[p].y = 0.f;
  }
  const float Dc = Ds[k * DI + c96];

  const int emit0 = ci * CL;
  const int lstart = (emit0 - NWARM > 0) ? (emit0 - NWARM) : 0;
  const int lend = emit0 + CL;
  const size_t bk = (size_t)(b * KG_ + k);

  for (int s = lstart; s < lend; s += STG) {
    __syncthreads();
    {
      const size_t dbase = (bk * L_ + s) * DI;
      const int pbase = rev ? (L_ - 1 - s) : s;
      const int psgn  = rev ? -1 : 1;
      const float* ubase = xxc + ((size_t)b * L_ + pbase) * DI + c96;
#pragma unroll
      for (int it = 0; it < 4; ++it) {
        const int t = r96 + 8 * it;
        const float dl = __bfloat162float(delta[dbase + (size_t)t * DI + c96]);
        const float uu = ubase[(ptrdiff_t)psgn * t * DI];
        f32x2 v; v.x = dl; v.y = dl * uu;
        *(f32x2*)&s_du[t][2 * c96] = v;
        s_u[t][c96] = uu;
      }
      const size_t nbase = (bk * L_ + s) * NS;
#pragma unroll
      for (int it = 0; it < 3; ++it) {
        const int t = r64 + 12 * it;
        if (t < STG) {
          s_B[t][c64] = __bfloat162float(Bs[nbase + (size_t)t * NS + c64]);
          s_C[t][c64] = __bfloat162float(Cs[nbase + (size_t)t * NS + c64]);
        }
      }
    }
    __syncthreads();
    const bool emit = (s >= emit0);
#pragma unroll 8
    for (int t = 0; t < STG; ++t) {
      const f32x2 du = *(const f32x2*)&s_du[t][2 * d];
      const float dlt = du.x, bu = du.y;
      const f32x2 dlt2 = {dlt, dlt};
      const f32x2 bu2 = {bu, bu};
      const f32x4 Bv0 = *(const f32x4*)&s_B[t][jn];
      const f32x4 Bv1 = *(const f32x4*)&s_B[t][jn + 4];
      const f32x4 Cv0 = *(const f32x4*)&s_C[t][jn];
      const f32x4 Cv1 = *(const f32x4*)&s_C[t][jn + 4];
      const f32x2 bp[4] = {{Bv0.x, Bv0.y}, {Bv0.z, Bv0.w},
                           {Bv1.x, Bv1.y}, {Bv1.z, Bv1.w}};
      const f32x2 cp[4] = {{Cv0.x, Cv0.y}, {Cv0.z, Cv0.w},
                           {Cv1.x, Cv1.y}, {Cv1.z, Cv1.w}};
      f32x2 y2 = {0.f, 0.f};
#pragma unroll
      for (int p = 0; p < 4; ++p) {
        const f32x2 arg = dlt2 * a2[p];
        f32x2 e;
        e.x = EXP2F(arg.x);
        e.y = EXP2F(arg.y);
        h[p] = e * h[p] + bu2 * bp[p];
        y2 += h[p] * cp[p];
      }
      float y = y2.x + y2.y;
      y += __shfl_xor(y, 1);
      y += __shfl_xor(y, 2);
      y += __shfl_xor(y, 4);
      if (emit && j == 0) s_y[t][d] = y;
    }
    if (emit) {
      __syncthreads();
      const int pbase = rev ? (L_ - 1 - s) : s;
      const int psgn  = rev ? -1 : 1;
      float* ybase = ysum + ((size_t)b * L_ + pbase) * DI + c96;
#pragma unroll
      for (int it = 0; it < 4; ++it) {
        const int t = r96 + 8 * it;
        atomicAdd(ybase + (ptrdiff_t)psgn * t * DI,
                  fmaf(Dc, s_u[t][c96], s_y[t][c96]));
      }
    }
  }
}

// ---------------- K5: out = (ysum .* zg) @ Wout^T -------------------------
__global__ __launch_bounds__(256) void k_out(
    const float* __restrict__ ysum, const float* __restrict__ zg,
    const float* __restrict__ wout, float* __restrict__ out)
{
  __shared__ float sa[64][100];
  __shared__ float sw[96][100];
  const int tid = threadIdx.x;
  const int lt = blockIdx.x, b = blockIdx.y;
  const int l0 = lt * 64;
  const size_t rbase = ((size_t)b * L_ + l0) * DI;

  for (int i = tid; i < 64 * 24; i += 256) {
    const int r = i / 24, q = i % 24;
    float4 av = reinterpret_cast<const float4*>(ysum + rbase + (size_t)r * DI)[q];
    const float4 zv = reinterpret_cast<const float4*>(zg + rbase + (size_t)r * DI)[q];
    av.x *= zv.x; av.y *= zv.y; av.z *= zv.z; av.w *= zv.w;
    *reinterpret_cast<float4*>(&sa[r][q * 4]) = av;
  }
  for (int i = tid; i < 96 * 24; i += 256) {
    const int r = i / 24, q = i % 24;
    const float4 v = reinterpret_cast<const float4*>(wout + (size_t)r * DM)[q];
    *reinterpret_cast<float4*>(&sw[r][q * 4]) = v;
  }
  __syncthreads();

  const int rg = tid & 15, cg = tid >> 4;
  float acc[4][6];
#pragma unroll
  for (int i = 0; i < 4; ++i)
#pragma unroll
    for (int jj = 0; jj < 6; ++jj) acc[i][jj] = 0.f;

  for (int d0 = 0; d0 < 96; d0 += 4) {
    float4 a[4], wv[6];
#pragma unroll
    for (int i = 0; i < 4; ++i)
      a[i] = *reinterpret_cast<const float4*>(&sa[rg + 16 * i][d0]);
#pragma unroll
    for (int jj = 0; jj < 6; ++jj)
      wv[jj] = *reinterpret_cast<const float4*>(&sw[cg + 16 * jj][d0]);
#pragma unroll
    for (int i = 0; i < 4; ++i)
#pragma unroll
      for (int jj = 0; jj < 6; ++jj)
        acc[i][jj] += a[i].x * wv[jj].x + a[i].y * wv[jj].y
                    + a[i].z * wv[jj].z + a[i].w * wv[jj].w;
  }

  __syncthreads();
  float* sout = &sw[0][0];  // reuse as [64][100]
#pragma unroll
  for (int i = 0; i < 4; ++i)
#pragma unroll
    for (int jj = 0; jj < 6; ++jj)
      sout[(rg + 16 * i) * 100 + (cg + 16 * jj)] = acc[i][jj];
  __syncthreads();

  float* op = out + ((size_t)b * L_ + l0) * DM;
  for (int i = tid; i < 64 * 24; i += 256) {
    const int r = i / 24, q = i % 24;
    const float4 v = *reinterpret_cast<const float4*>(&sout[r * 100 + q * 4]);
    reinterpret_cast<float4*>(op + (size_t)r * DM)[q] = v;
  }
}

extern "C" void kernel_launch(void* const* d_in, const int* in_sizes, int n_in,
                              void* d_out, int out_size, void* d_ws, size_t ws_size,
                              hipStream_t stream)
{
  const float* x    = (const float*)d_in[0];
  const float* ipw  = (const float*)d_in[1];
  const float* cw   = (const float*)d_in[2];
  const float* xpw  = (const float*)d_in[3];
  const float* dtw  = (const float*)d_in[4];
  const float* opw  = (const float*)d_in[5];
  const float* alog = (const float*)d_in[6];
  const float* dsv  = (const float*)d_in[7];
  float* out = (float*)d_out;
  char* ws = (char*)d_ws;

  const size_t SZ_XZ  = (size_t)B_ * L_ * 192 * 4;      // region reserved (delta lives here)
  const size_t SZ_F   = (size_t)B_ * L_ * DI * 4;       // 25,165,824
  const size_t SZ_NBF = (size_t)B_ * KG_ * L_ * NS * 2; // 33,554,432

  __hip_bfloat16* dlt  = (__hip_bfloat16*)ws;
  float* xxc           = (float*)(ws + SZ_XZ);
  float* zgp           = (float*)(ws + SZ_XZ + SZ_F);
  __hip_bfloat16* Bsp  = (__hip_bfloat16*)(ws + SZ_XZ + 2 * SZ_F);
  __hip_bfloat16* Csp  = (__hip_bfloat16*)(ws + SZ_XZ + 2 * SZ_F + SZ_NBF);
  float* ysum          = (float*)(ws + SZ_XZ + 2 * SZ_F + 2 * SZ_NBF);

  hipMemsetAsync(ysum, 0, SZ_F, stream);
  k_front  <<<dim3(L_ / 64, 2, B_),   256, 0, stream>>>(x, ipw, cw, xxc, zgp);
  k_xproj  <<<dim3(L_ / 64, KG_, B_), 256, 0, stream>>>(xxc, xpw, dtw, dlt, Bsp, Csp);
  k_scan   <<<dim3(NC, KG_, B_),      768, 0, stream>>>(xxc, dlt, Bsp, Csp, alog, dsv, ysum);
  k_out    <<<dim3(L_ / 64, B_),      256, 0, stream>>>(ysum, zgp, opw, out);
}